// Round 2
// baseline (745.481 us; speedup 1.0000x reference)
//
#include <hip/hip_runtime.h>

#define N_NODES 50000
#define N_EDGES 800000
#define F 64
#define EDIM 16
#define NUM_CONV 3
#define NEG_SLOPE 0.01f

// ---------------- edge kernel: e_proj + gather + relu + scatter-sum ----------------
__global__ __launch_bounds__(256) void edge_kernel(
    const float* __restrict__ h,
    const int* __restrict__ ei,         // [2, E] (int32 per harness contract)
    const float* __restrict__ ea,       // [E, 16]
    const float* __restrict__ We,       // [16, 64] (layer slice)
    const float* __restrict__ be,       // [64]
    float* __restrict__ aggr)           // [N, 64], pre-zeroed
{
    __shared__ float Ws[EDIM * F];
    __shared__ float bs[F];
    for (int i = threadIdx.x; i < EDIM * F; i += blockDim.x) Ws[i] = We[i];
    if (threadIdx.x < F) bs[threadIdx.x] = be[threadIdx.x];
    __syncthreads();

    const int lane = threadIdx.x & 63;
    const int wid  = threadIdx.x >> 6;
    const int wavesPerGrid = gridDim.x * (blockDim.x >> 6);

    for (int e = blockIdx.x * (blockDim.x >> 6) + wid; e < N_EDGES; e += wavesPerGrid) {
        const int s = ei[e];
        const int d = ei[N_EDGES + e];
        const float4* ea4 = (const float4*)(ea + (size_t)e * EDIM);
        float acc = bs[lane];
#pragma unroll
        for (int k4 = 0; k4 < 4; ++k4) {
            float4 v = ea4[k4];
            acc += v.x * Ws[(k4 * 4 + 0) * F + lane];
            acc += v.y * Ws[(k4 * 4 + 1) * F + lane];
            acc += v.z * Ws[(k4 * 4 + 2) * F + lane];
            acc += v.w * Ws[(k4 * 4 + 3) * F + lane];
        }
        float m = h[(size_t)s * F + lane] + acc;
        m = m > 0.f ? m : 0.f;          // ReLU
        atomicAdd(&aggr[(size_t)d * F + lane], m);
    }
}

// ---------------- node update: (h + aggr) @ Wn + bn, then LeakyReLU ----------------
__global__ __launch_bounds__(256) void node_kernel(
    const float* __restrict__ h,
    const float* __restrict__ aggr,
    const float* __restrict__ Wn,       // [64, 64]
    const float* __restrict__ bn,       // [64]
    float* __restrict__ hout)
{
    __shared__ float Ws[F * F];
    __shared__ float bs[F];
    for (int i = threadIdx.x; i < F * F; i += blockDim.x) Ws[i] = Wn[i];
    if (threadIdx.x < F) bs[threadIdx.x] = bn[threadIdx.x];
    __syncthreads();

    const int lane = threadIdx.x & 63;
    const int wid  = threadIdx.x >> 6;
    const int wavesPerGrid = gridDim.x * (blockDim.x >> 6);

    for (int n = blockIdx.x * (blockDim.x >> 6) + wid; n < N_NODES; n += wavesPerGrid) {
        float t = h[(size_t)n * F + lane] + aggr[(size_t)n * F + lane];
        float acc = bs[lane];
#pragma unroll
        for (int k = 0; k < F; ++k) {
            acc += __shfl(t, k) * Ws[k * F + lane];
        }
        acc = acc >= 0.f ? acc : NEG_SLOPE * acc;   // LeakyReLU
        hout[(size_t)n * F + lane] = acc;
    }
}

// ---------------- fuse readout weights: Wf = W1@W2 [64,2], bf = b1@W2 + b2 [2] ----------------
__global__ void fuse_weights_kernel(
    const float* __restrict__ W1,  // [64,128]
    const float* __restrict__ b1,  // [128]
    const float* __restrict__ W2,  // [128,2]
    const float* __restrict__ b2,  // [2]
    float* __restrict__ Wf,        // [64,2]
    float* __restrict__ bf)        // [2]
{
    const int t = threadIdx.x;     // 128 threads
    const int i = t >> 1;
    const int j = t & 1;
    float acc = 0.f;
    for (int k = 0; k < 128; ++k) acc += W1[i * 128 + k] * W2[k * 2 + j];
    Wf[i * 2 + j] = acc;
    if (i == 0) {
        float accb = b2[j];
        for (int k = 0; k < 128; ++k) accb += b1[k] * W2[k * 2 + j];
        bf[j] = accb;
    }
}

// ---------------- readout: out = h @ Wf + bf ----------------
__global__ __launch_bounds__(256) void readout_kernel(
    const float* __restrict__ h,
    const float* __restrict__ Wf,
    const float* __restrict__ bf,
    float* __restrict__ out)
{
    __shared__ float Ws[F * 2];
    __shared__ float bs[2];
    for (int i = threadIdx.x; i < F * 2; i += blockDim.x) Ws[i] = Wf[i];
    if (threadIdx.x < 2) bs[threadIdx.x] = bf[threadIdx.x];
    __syncthreads();

    for (int n = blockIdx.x * blockDim.x + threadIdx.x; n < N_NODES;
         n += gridDim.x * blockDim.x) {
        const float4* hp = (const float4*)(h + (size_t)n * F);
        float a0 = bs[0], a1 = bs[1];
#pragma unroll
        for (int k4 = 0; k4 < 16; ++k4) {
            float4 v = hp[k4];
            a0 += v.x * Ws[(k4 * 4 + 0) * 2 + 0] + v.y * Ws[(k4 * 4 + 1) * 2 + 0]
                + v.z * Ws[(k4 * 4 + 2) * 2 + 0] + v.w * Ws[(k4 * 4 + 3) * 2 + 0];
            a1 += v.x * Ws[(k4 * 4 + 0) * 2 + 1] + v.y * Ws[(k4 * 4 + 1) * 2 + 1]
                + v.z * Ws[(k4 * 4 + 2) * 2 + 1] + v.w * Ws[(k4 * 4 + 3) * 2 + 1];
        }
        out[(size_t)n * 2 + 0] = a0;
        out[(size_t)n * 2 + 1] = a1;
    }
}

extern "C" void kernel_launch(void* const* d_in, const int* in_sizes, int n_in,
                              void* d_out, int out_size, void* d_ws, size_t ws_size,
                              hipStream_t stream) {
    const float* x  = (const float*)d_in[0];
    const int*   ei = (const int*)d_in[1];       // int32 per harness contract
    const float* ea = (const float*)d_in[2];
    const float* Wn = (const float*)d_in[3];
    const float* bn = (const float*)d_in[4];
    const float* We = (const float*)d_in[5];     // [3,16,64]
    const float* be = (const float*)d_in[6];     // [3,64]
    const float* W1 = (const float*)d_in[7];
    const float* b1 = (const float*)d_in[8];
    const float* W2 = (const float*)d_in[9];
    const float* b2 = (const float*)d_in[10];
    float* out = (float*)d_out;

    float* ws   = (float*)d_ws;
    float* hA   = ws;
    float* hB   = hA + (size_t)N_NODES * F;
    float* aggr = hB + (size_t)N_NODES * F;
    float* Wf   = aggr + (size_t)N_NODES * F;
    float* bf   = Wf + F * 2;

    // readout-weight fusion is independent of the conv layers; launch first
    fuse_weights_kernel<<<1, 128, 0, stream>>>(W1, b1, W2, b2, Wf, bf);

    // h0 = x
    hipMemcpyAsync(hA, x, sizeof(float) * (size_t)N_NODES * F,
                   hipMemcpyDeviceToDevice, stream);

    float* hcur = hA;
    float* hnext = hB;
    for (int l = 0; l < NUM_CONV; ++l) {
        hipMemsetAsync(aggr, 0, sizeof(float) * (size_t)N_NODES * F, stream);
        edge_kernel<<<2048, 256, 0, stream>>>(hcur, ei, ea,
                                              We + (size_t)l * EDIM * F,
                                              be + (size_t)l * F, aggr);
        node_kernel<<<2048, 256, 0, stream>>>(hcur, aggr, Wn, bn, hnext);
        float* tmp = hcur; hcur = hnext; hnext = tmp;
    }

    readout_kernel<<<196, 256, 0, stream>>>(hcur, Wf, bf, out);
}